// Round 13
// baseline (459.606 us; speedup 1.0000x reference)
//
#include <hip/hip_runtime.h>

#define N_NODES 200000
#define N_EDGES 400000
#define N_GRAPHS 64
#define HDIM 128
#define INDIM 5
#define LN_EPS 1e-5f
#define LDA 138  // 69 words/row, 69 mod 32 = 5 (coprime) -> conflict-distributed LDS reads
#define NPBLK 32 // nodes per block (2 waves x 16 rows)

typedef __attribute__((ext_vector_type(8))) short short8;
typedef __attribute__((ext_vector_type(4))) float f32x4;

__device__ __forceinline__ unsigned short to_bf(float v) {
    unsigned u = __builtin_bit_cast(unsigned, v);
    return (unsigned short)((u + 0x7FFFu + ((u >> 16) & 1u)) >> 16);
}
__device__ __forceinline__ float bf_lo(unsigned w) { return __builtin_bit_cast(float, w << 16); }
__device__ __forceinline__ float bf_hi(unsigned w) { return __builtin_bit_cast(float, w & 0xFFFF0000u); }
__device__ __forceinline__ float bf2f(unsigned short h) { return __builtin_bit_cast(float, (unsigned)h << 16); }

// ---------------- CSR build ----------------

__global__ void hist_kernel(const int* __restrict__ ei, int* __restrict__ deg) {
    int e = blockIdx.x * blockDim.x + threadIdx.x;
    if (e < N_EDGES) atomicAdd(&deg[ei[N_EDGES + e]], 1);
}

#define SCAN_CHUNK 1024
#define SCAN_BLOCKS ((N_NODES + SCAN_CHUNK - 1) / SCAN_CHUNK)  // 196

__global__ __launch_bounds__(256) void scan_phaseA(const int* __restrict__ deg, int* __restrict__ bsums) {
    __shared__ int red[256];
    int t = threadIdx.x;
    int base = blockIdx.x * SCAN_CHUNK + t * 4;
    int s = 0;
#pragma unroll
    for (int k = 0; k < 4; ++k) {
        int i = base + k;
        s += (i < N_NODES) ? deg[i] : 0;
    }
    red[t] = s;
    __syncthreads();
    for (int off = 128; off; off >>= 1) {
        if (t < off) red[t] += red[t + off];
        __syncthreads();
    }
    if (t == 0) bsums[blockIdx.x] = red[0];
}

__global__ __launch_bounds__(256) void scan_phaseB(int* __restrict__ bsums, int* __restrict__ row_ptr) {
    __shared__ int s[256];
    int t = threadIdx.x;
    int v = (t < SCAN_BLOCKS) ? bsums[t] : 0;
    s[t] = v;
    __syncthreads();
    for (int off = 1; off < 256; off <<= 1) {
        int add = (t >= off) ? s[t - off] : 0;
        __syncthreads();
        s[t] += add;
        __syncthreads();
    }
    if (t < SCAN_BLOCKS) bsums[t] = s[t] - v;  // exclusive
    if (t == SCAN_BLOCKS - 1) row_ptr[N_NODES] = s[t];
}

__global__ __launch_bounds__(256) void scan_phaseC(const int* __restrict__ deg,
                                                   const int* __restrict__ bsums,
                                                   int* __restrict__ row_ptr) {
    __shared__ int ts[256];
    int t = threadIdx.x;
    int base = blockIdx.x * SCAN_CHUNK + t * 4;
    int v[4];
    int s = 0;
#pragma unroll
    for (int k = 0; k < 4; ++k) {
        int i = base + k;
        v[k] = (i < N_NODES) ? deg[i] : 0;
        s += v[k];
    }
    ts[t] = s;
    __syncthreads();
    for (int off = 1; off < 256; off <<= 1) {
        int add = (t >= off) ? ts[t - off] : 0;
        __syncthreads();
        ts[t] += add;
        __syncthreads();
    }
    int run = bsums[blockIdx.x] + ts[t] - s;
#pragma unroll
    for (int k = 0; k < 4; ++k) {
        int i = base + k;
        if (i < N_NODES) row_ptr[i] = run;
        run += v[k];
    }
}

// packed CSR record: {src, float-bits(val)}
__global__ void scatter_kernel(const int* __restrict__ ei, const float* __restrict__ ea,
                               const int* __restrict__ row_ptr, int* __restrict__ cursor,
                               int2* __restrict__ csr) {
    int e = blockIdx.x * blockDim.x + threadIdx.x;
    if (e >= N_EDGES) return;
    int d = ei[N_EDGES + e];
    int pos = atomicAdd(&cursor[d], 1);
    csr[row_ptr[d] + pos] = make_int2(ei[e], __float_as_int(ea[e]));
}

// ---------------- Weight packing: all 6 matrices in one launch ----------------
__global__ void pack_all(const float* __restrict__ s0, short* __restrict__ d0,
                         const float* __restrict__ s1, short* __restrict__ d1,
                         const float* __restrict__ s2, short* __restrict__ d2,
                         const float* __restrict__ s3, short* __restrict__ d3,
                         const float* __restrict__ s4, short* __restrict__ d4,
                         const float* __restrict__ s5, short* __restrict__ d5) {
    int b = blockIdx.x;
    const float* W;
    short* D;
    int din, KP, b0;
    if (b < 16)       { W = s0; D = d0; din = 5;   KP = 32;  b0 = 0; }
    else if (b < 80)  { W = s1; D = d1; din = 128; KP = 128; b0 = 16; }
    else if (b < 144) { W = s2; D = d2; din = 128; KP = 128; b0 = 80; }
    else if (b < 208) { W = s3; D = d3; din = 128; KP = 128; b0 = 144; }
    else if (b < 272) { W = s4; D = d4; din = 128; KP = 128; b0 = 208; }
    else              { W = s5; D = d5; din = 128; KP = 128; b0 = 272; }
    int idx = (b - b0) * 256 + threadIdx.x;
    if (idx >= KP * 128) return;
    int j = idx & 7;
    int lane = (idx >> 3) & 63;
    int rest = idx >> 9;
    int KS = KP >> 5;
    int kstep = rest % KS;
    int tile = rest / KS;
    int k = kstep * 32 + ((lane >> 4) * 8) + j;
    int n = tile * 16 + (lane & 15);
    float v = (k < din) ? W[k * 128 + n] : 0.f;
    D[idx] = (short)to_bf(v);
}

// ---------------- Fused layer: gather + MFMA MLP + reg-LN + ReLU (+pool) ----------------
// 128 threads = 2 waves; 32 nodes/block; each wave owns its 16 rows end-to-end.
// Non-pool layers: ONE barrier total (eweb staging) -- waves fully decoupled after it.
template <int KP1, bool POOL>
__global__ __launch_bounds__(128, 5) void layer_fused(
    const void* __restrict__ xin_v, const int* __restrict__ row_ptr,
    const int2* __restrict__ csr,
    const float* __restrict__ ew, const float* __restrict__ eb,
    const short* __restrict__ w1h, const float* __restrict__ b1,
    const short* __restrict__ w2h, const float* __restrict__ b2,
    const float* __restrict__ g, const float* __restrict__ bt,
    unsigned short* __restrict__ xout,
    const int* __restrict__ batch, float* __restrict__ pool, int* __restrict__ cnt) {
    __shared__ __align__(16) unsigned short A16[NPBLK * LDA];
    __shared__ int bidx[NPBLK];
    union Scratch {
        float eweb[256];                    // [0..127]=ew, [128..255]=eb  (din=128 path)
        float part[NPBLK][4][INDIM];        // layer-0 gather partials
    };
    __shared__ Scratch u;

    int tid = threadIdx.x;
    int node0 = blockIdx.x * NPBLK;

    if (KP1 == 128) {
        const unsigned short* xin = (const unsigned short*)xin_v;
        // stage ew/eb to LDS
        if (tid < 32) ((float4*)u.eweb)[tid] = ((const float4*)ew)[tid];
        else if (tid < 64) ((float4*)u.eweb)[tid] = ((const float4*)eb)[tid - 32];
        if (POOL && tid >= 64 && tid < 96) bidx[tid - 64] = batch[node0 + tid - 64];

        // thread = (row, 32-channel quarter); f32 accumulators in registers
        int row = tid >> 2, qt = tid & 3, c0 = qt * 32;
        int node = node0 + row;
        float acc[32];
        {
            const uint4* xn = (const uint4*)(xin + (size_t)node * 128 + c0);
            uint4 uv[4];
#pragma unroll
            for (int j = 0; j < 4; ++j) uv[j] = xn[j];
            unsigned wds[16] = {uv[0].x, uv[0].y, uv[0].z, uv[0].w,
                                uv[1].x, uv[1].y, uv[1].z, uv[1].w,
                                uv[2].x, uv[2].y, uv[2].z, uv[2].w,
                                uv[3].x, uv[3].y, uv[3].z, uv[3].w};
#pragma unroll
            for (int i = 0; i < 16; ++i) {
                acc[2 * i] = bf_lo(wds[i]);
                acc[2 * i + 1] = bf_hi(wds[i]);
            }
        }
        int beg = row_ptr[node], end = row_ptr[node + 1];
        __syncthreads();  // eweb ready (the only barrier on this path)

        for (int e = beg; e < end; ++e) {
            int2 r = csr[e];
            float a = __int_as_float(r.y);
            const uint4* xs = (const uint4*)(xin + (size_t)r.x * 128 + c0);
            uint4 uv[4];
#pragma unroll
            for (int j = 0; j < 4; ++j) uv[j] = xs[j];
            unsigned wds[16] = {uv[0].x, uv[0].y, uv[0].z, uv[0].w,
                                uv[1].x, uv[1].y, uv[1].z, uv[1].w,
                                uv[2].x, uv[2].y, uv[2].z, uv[2].w,
                                uv[3].x, uv[3].y, uv[3].z, uv[3].w};
#pragma unroll
            for (int i = 0; i < 16; ++i) {
                int cA = c0 + 2 * i, cB = cA + 1;
                acc[2 * i] += fmaxf(fmaf(a, u.eweb[cA], bf_lo(wds[i]) + u.eweb[128 + cA]), 0.f);
                acc[2 * i + 1] += fmaxf(fmaf(a, u.eweb[cB], bf_hi(wds[i]) + u.eweb[128 + cB]), 0.f);
            }
        }
        unsigned* Ar = (unsigned*)&A16[row * LDA + c0];
#pragma unroll
        for (int i = 0; i < 16; ++i)
            Ar[i] = (unsigned)to_bf(acc[2 * i]) | ((unsigned)to_bf(acc[2 * i + 1]) << 16);
        // no barrier: rows [16wv,16wv+16) are written and read by the same wave
    } else {
        // layer 0 (din=5): 4 threads/row split the edge list; register partials
        const float* xinf = (const float*)xin_v;
        int row = tid >> 2, qt = tid & 3;
        int node = node0 + row;
        if (POOL && tid >= 64 && tid < 96) bidx[tid - 64] = batch[node0 + tid - 64];
        {
            float w[INDIM], b[INDIM], acc[INDIM];
#pragma unroll
            for (int j = 0; j < INDIM; ++j) {
                w[j] = ew[j];
                b[j] = eb[j];
                acc[j] = 0.f;
            }
            int beg = row_ptr[node], end = row_ptr[node + 1];
            for (int e = beg + qt; e < end; e += 4) {
                int2 r = csr[e];
                float a = __int_as_float(r.y);
#pragma unroll
                for (int j = 0; j < INDIM; ++j)
                    acc[j] += fmaxf(fmaf(a, w[j], xinf[r.x * INDIM + j] + b[j]), 0.f);
            }
#pragma unroll
            for (int j = 0; j < INDIM; ++j) u.part[row][qt][j] = acc[j];
        }
        __syncthreads();
        if (tid < NPBLK) {
#pragma unroll
            for (int j = 0; j < INDIM; ++j) {
                float v = xinf[(node0 + tid) * INDIM + j] + u.part[tid][0][j] + u.part[tid][1][j] +
                          u.part[tid][2][j] + u.part[tid][3][j];
                A16[tid * LDA + j] = to_bf(v);
            }
#pragma unroll
            for (int j = INDIM; j < 32; ++j) A16[tid * LDA + j] = 0;
        }
        __syncthreads();  // rows written by wave0 only -> cross-wave
    }

    // ---- MFMA MLP (wave-local rows) ----
    int wv = tid >> 6, lane = tid & 63;
    int mrow = lane & 15, q = lane >> 4;
    int arow = wv * 16 + mrow;

    const short8* w1p = (const short8*)w1h;
    const short8* w2p = (const short8*)w2h;

    f32x4 acc2[8];
#pragma unroll
    for (int t = 0; t < 8; ++t) acc2[t] = (f32x4){0.f, 0.f, 0.f, 0.f};
    constexpr int KS1 = KP1 / 32;
#pragma unroll
    for (int ks = 0; ks < KS1; ++ks) {
        short8 bh[8];
#pragma unroll
        for (int t = 0; t < 8; ++t) bh[t] = w1p[((size_t)t * KS1 + ks) * 64 + lane];
        short8 ah = *(const short8*)&A16[arow * LDA + ks * 32 + q * 8];
#pragma unroll
        for (int t = 0; t < 8; ++t)
            acc2[t] = __builtin_amdgcn_mfma_f32_16x16x32_bf16(ah, bh[t], acc2[t], 0, 0, 0);
    }
    // t1 = relu(acc + b1) -> bf16 A (wave-local rows)
    {
        float b1v[8];
#pragma unroll
        for (int t = 0; t < 8; ++t) b1v[t] = b1[t * 16 + mrow];
#pragma unroll
        for (int t = 0; t < 8; ++t)
#pragma unroll
            for (int r = 0; r < 4; ++r) {
                int rrow = wv * 16 + q * 4 + r;
                int col = t * 16 + mrow;
                A16[rrow * LDA + col] = to_bf(fmaxf(acc2[t][r] + b1v[t], 0.f));
            }
    }

    // GEMM2 (K = 128); A reads wave-local
#pragma unroll
    for (int t = 0; t < 8; ++t) acc2[t] = (f32x4){0.f, 0.f, 0.f, 0.f};
#pragma unroll
    for (int ks = 0; ks < 4; ++ks) {
        short8 bh[8];
#pragma unroll
        for (int t = 0; t < 8; ++t) bh[t] = w2p[((size_t)t * 4 + ks) * 64 + lane];
        short8 ah = *(const short8*)&A16[arow * LDA + ks * 32 + q * 8];
#pragma unroll
        for (int t = 0; t < 8; ++t)
            acc2[t] = __builtin_amdgcn_mfma_f32_16x16x32_bf16(ah, bh[t], acc2[t], 0, 0, 0);
    }

    // ---- LayerNorm in registers (rows live in 16-lane groups) ----
    float s4[4] = {0.f, 0.f, 0.f, 0.f}, q4[4] = {0.f, 0.f, 0.f, 0.f};
    {
        float b2v[8];
#pragma unroll
        for (int t = 0; t < 8; ++t) b2v[t] = b2[t * 16 + mrow];
#pragma unroll
        for (int t = 0; t < 8; ++t)
#pragma unroll
            for (int r = 0; r < 4; ++r) {
                float v = acc2[t][r] + b2v[t];
                acc2[t][r] = v;
                s4[r] += v;
                q4[r] += v * v;
            }
    }
#pragma unroll
    for (int m = 1; m <= 8; m <<= 1) {
#pragma unroll
        for (int r = 0; r < 4; ++r) {
            s4[r] += __shfl_xor(s4[r], m, 64);
            q4[r] += __shfl_xor(q4[r], m, 64);
        }
    }
    float mu[4], inv[4];
#pragma unroll
    for (int r = 0; r < 4; ++r) {
        mu[r] = s4[r] * (1.f / HDIM);
        float var = q4[r] * (1.f / HDIM) - mu[r] * mu[r];
        inv[r] = rsqrtf(var + LN_EPS);
    }
    float gv[8], btv[8];
#pragma unroll
    for (int t = 0; t < 8; ++t) {
        gv[t] = g[t * 16 + mrow];
        btv[t] = bt[t * 16 + mrow];
    }

    // LN result -> LDS (wave-local row writes)
#pragma unroll
    for (int t = 0; t < 8; ++t)
#pragma unroll
        for (int r = 0; r < 4; ++r) {
            int rrow = wv * 16 + q * 4 + r;
            int col = t * 16 + mrow;
            float o = fmaxf((acc2[t][r] - mu[r]) * inv[r] * gv[t] + btv[t], 0.f);
            A16[rrow * LDA + col] = to_bf(o);
        }

    if (!POOL) {
        // wave-local coalesced copy-out: each wave stores only its own 16 rows.
        // One wave-inst = 64 lanes x 4B = one full 256-B row. NO block barrier.
        unsigned* xo = (unsigned*)xout;
#pragma unroll
        for (int rr = 0; rr < 16; ++rr) {
            int row = wv * 16 + rr;
            xo[(size_t)(node0 + row) * 64 + lane] = ((const unsigned*)&A16[row * LDA])[lane];
        }
    } else {
        __syncthreads();  // pool scan reads all 32 rows
        {
            int col = tid;  // 128 threads = 128 cols
            float accp = 0.f;
            int cur = bidx[0];
            for (int r = 0; r < NPBLK; ++r) {
                int gi = bidx[r];
                if (gi != cur) {
                    unsafeAtomicAdd(&pool[cur * HDIM + col], accp);
                    accp = 0.f;
                    cur = gi;
                }
                accp += bf2f(A16[r * LDA + col]);
            }
            unsafeAtomicAdd(&pool[cur * HDIM + col], accp);
        }
        if (tid == 0) {
            int cur = bidx[0], c = 0;
            for (int r = 0; r < NPBLK; ++r) {
                if (bidx[r] != cur) {
                    atomicAdd(&cnt[cur], c);
                    c = 0;
                    cur = bidx[r];
                }
                ++c;
            }
            atomicAdd(&cnt[cur], c);
        }
    }
}

__global__ void pool_final(const float* __restrict__ pool, const int* __restrict__ cnt,
                           float* __restrict__ out) {
    int g = blockIdx.x, j = threadIdx.x;
    float add = pool[g * HDIM + j];
    float c = (float)max(cnt[g], 1);
    out[g * (2 * HDIM) + j] = add / c;
    out[g * (2 * HDIM) + HDIM + j] = add;
}

extern "C" void kernel_launch(void* const* d_in, const int* in_sizes, int n_in,
                              void* d_out, int out_size, void* d_ws, size_t ws_size,
                              hipStream_t stream) {
    const float* x_in = (const float*)d_in[0];
    const int* ei = (const int*)d_in[1];
    const float* ea = (const float*)d_in[2];
    const int* batch = (const int*)d_in[3];
    const float* P[24];
    for (int i = 0; i < 24; ++i) P[i] = (const float*)d_in[4 + i];
    // per layer l (base 8l): 0=ew 1=eb 2=w1 3=b1 4=w2 5=b2 6=g 7=bt

    unsigned short* x_a = (unsigned short*)d_ws;                 // N*128 bf16
    unsigned short* x_b = x_a + (size_t)N_NODES * HDIM;          // N*128 bf16
    float* pool = (float*)(x_b + (size_t)N_NODES * HDIM);        // G*128 } zeroed
    int* cnt = (int*)(pool + N_GRAPHS * HDIM);                   // G     } together
    int* deg = cnt + N_GRAPHS;                                   // N
    int* cursor = deg + N_NODES;                                 // N
    int* row_ptr = cursor + N_NODES;                             // N+1
    int* bsums = row_ptr + N_NODES + 1;                          // pad 256 (keeps int2 8B-aligned)
    int2* csr = (int2*)(bsums + 256);                            // E (packed {src, val})
    short* wp = (short*)(((uintptr_t)(csr + N_EDGES) + 15) & ~(uintptr_t)15);
    float* out = (float*)d_out;

    short *w1h[3], *w2h[3];
    for (int l = 0; l < 3; ++l) {
        w1h[l] = wp + (size_t)l * 32768;
        w2h[l] = w1h[l] + 16384;
    }

    // ---- single memset: pool + cnt + deg + cursor ----
    hipMemsetAsync(pool, 0,
                   (N_GRAPHS * HDIM + N_GRAPHS + 2 * N_NODES) * sizeof(int), stream);

    // ---- CSR build ----
    hist_kernel<<<(N_EDGES + 255) / 256, 256, 0, stream>>>(ei, deg);
    scan_phaseA<<<SCAN_BLOCKS, 256, 0, stream>>>(deg, bsums);
    scan_phaseB<<<1, 256, 0, stream>>>(bsums, row_ptr);
    scan_phaseC<<<SCAN_BLOCKS, 256, 0, stream>>>(deg, bsums, row_ptr);
    scatter_kernel<<<(N_EDGES + 255) / 256, 256, 0, stream>>>(ei, ea, row_ptr, cursor, csr);

    // ---- pack all weights in one launch (16 + 5*64 = 336 blocks) ----
    pack_all<<<336, 256, 0, stream>>>(P[2], w1h[0], P[4], w2h[0],
                                      P[10], w1h[1], P[12], w2h[1],
                                      P[18], w1h[2], P[20], w2h[2]);

    // ---- fused layers ----
    layer_fused<32, false><<<N_NODES / NPBLK, 128, 0, stream>>>(
        x_in, row_ptr, csr, P[0], P[1],
        w1h[0], P[3], w2h[0], P[5], P[6], P[7], x_a, nullptr, nullptr, nullptr);
    layer_fused<128, false><<<N_NODES / NPBLK, 128, 0, stream>>>(
        x_a, row_ptr, csr, P[8], P[9],
        w1h[1], P[11], w2h[1], P[13], P[14], P[15], x_b, nullptr, nullptr, nullptr);
    layer_fused<128, true><<<N_NODES / NPBLK, 128, 0, stream>>>(
        x_b, row_ptr, csr, P[16], P[17],
        w1h[2], P[19], w2h[2], P[21], P[22], P[23], nullptr, batch, pool, cnt);

    pool_final<<<N_GRAPHS, HDIM, 0, stream>>>(pool, cnt, out);
}

// Round 14
// 365.886 us; speedup vs baseline: 1.2561x; 1.2561x over previous
//
#include <hip/hip_runtime.h>

#define N_NODES 200000
#define N_EDGES 400000
#define N_GRAPHS 64
#define HDIM 128
#define INDIM 5
#define LN_EPS 1e-5f
#define LDA 138  // 69 words/row, 69 mod 32 = 5 (coprime) -> conflict-distributed LDS reads
#define NPBLK 32 // nodes per block (2 waves x 16 rows)

typedef __attribute__((ext_vector_type(8))) short short8;
typedef __attribute__((ext_vector_type(4))) float f32x4;

__device__ __forceinline__ unsigned short to_bf(float v) {
    unsigned u = __builtin_bit_cast(unsigned, v);
    return (unsigned short)((u + 0x7FFFu + ((u >> 16) & 1u)) >> 16);
}
__device__ __forceinline__ float bf_lo(unsigned w) { return __builtin_bit_cast(float, w << 16); }
__device__ __forceinline__ float bf_hi(unsigned w) { return __builtin_bit_cast(float, w & 0xFFFF0000u); }
__device__ __forceinline__ float bf2f(unsigned short h) { return __builtin_bit_cast(float, (unsigned)h << 16); }

// ---------------- CSR build ----------------

__global__ void hist_kernel(const int* __restrict__ ei, int* __restrict__ deg) {
    int e = blockIdx.x * blockDim.x + threadIdx.x;
    if (e < N_EDGES) atomicAdd(&deg[ei[N_EDGES + e]], 1);
}

#define SCAN_CHUNK 1024
#define SCAN_BLOCKS ((N_NODES + SCAN_CHUNK - 1) / SCAN_CHUNK)  // 196

__global__ __launch_bounds__(256) void scan_phaseA(const int* __restrict__ deg, int* __restrict__ bsums) {
    __shared__ int red[256];
    int t = threadIdx.x;
    int base = blockIdx.x * SCAN_CHUNK + t * 4;
    int s = 0;
#pragma unroll
    for (int k = 0; k < 4; ++k) {
        int i = base + k;
        s += (i < N_NODES) ? deg[i] : 0;
    }
    red[t] = s;
    __syncthreads();
    for (int off = 128; off; off >>= 1) {
        if (t < off) red[t] += red[t + off];
        __syncthreads();
    }
    if (t == 0) bsums[blockIdx.x] = red[0];
}

__global__ __launch_bounds__(256) void scan_phaseB(int* __restrict__ bsums, int* __restrict__ row_ptr) {
    __shared__ int s[256];
    int t = threadIdx.x;
    int v = (t < SCAN_BLOCKS) ? bsums[t] : 0;
    s[t] = v;
    __syncthreads();
    for (int off = 1; off < 256; off <<= 1) {
        int add = (t >= off) ? s[t - off] : 0;
        __syncthreads();
        s[t] += add;
        __syncthreads();
    }
    if (t < SCAN_BLOCKS) bsums[t] = s[t] - v;  // exclusive
    if (t == SCAN_BLOCKS - 1) row_ptr[N_NODES] = s[t];
}

__global__ __launch_bounds__(256) void scan_phaseC(const int* __restrict__ deg,
                                                   const int* __restrict__ bsums,
                                                   int* __restrict__ row_ptr) {
    __shared__ int ts[256];
    int t = threadIdx.x;
    int base = blockIdx.x * SCAN_CHUNK + t * 4;
    int v[4];
    int s = 0;
#pragma unroll
    for (int k = 0; k < 4; ++k) {
        int i = base + k;
        v[k] = (i < N_NODES) ? deg[i] : 0;
        s += v[k];
    }
    ts[t] = s;
    __syncthreads();
    for (int off = 1; off < 256; off <<= 1) {
        int add = (t >= off) ? ts[t - off] : 0;
        __syncthreads();
        ts[t] += add;
        __syncthreads();
    }
    int run = bsums[blockIdx.x] + ts[t] - s;
#pragma unroll
    for (int k = 0; k < 4; ++k) {
        int i = base + k;
        if (i < N_NODES) row_ptr[i] = run;
        run += v[k];
    }
}

// packed CSR record: {src, float-bits(val)}
__global__ void scatter_kernel(const int* __restrict__ ei, const float* __restrict__ ea,
                               const int* __restrict__ row_ptr, int* __restrict__ cursor,
                               int2* __restrict__ csr) {
    int e = blockIdx.x * blockDim.x + threadIdx.x;
    if (e >= N_EDGES) return;
    int d = ei[N_EDGES + e];
    int pos = atomicAdd(&cursor[d], 1);
    csr[row_ptr[d] + pos] = make_int2(ei[e], __float_as_int(ea[e]));
}

// ---------------- Weight packing: all 6 matrices in one launch ----------------
__global__ void pack_all(const float* __restrict__ s0, short* __restrict__ d0,
                         const float* __restrict__ s1, short* __restrict__ d1,
                         const float* __restrict__ s2, short* __restrict__ d2,
                         const float* __restrict__ s3, short* __restrict__ d3,
                         const float* __restrict__ s4, short* __restrict__ d4,
                         const float* __restrict__ s5, short* __restrict__ d5) {
    int b = blockIdx.x;
    const float* W;
    short* D;
    int din, KP, b0;
    if (b < 16)       { W = s0; D = d0; din = 5;   KP = 32;  b0 = 0; }
    else if (b < 80)  { W = s1; D = d1; din = 128; KP = 128; b0 = 16; }
    else if (b < 144) { W = s2; D = d2; din = 128; KP = 128; b0 = 80; }
    else if (b < 208) { W = s3; D = d3; din = 128; KP = 128; b0 = 144; }
    else if (b < 272) { W = s4; D = d4; din = 128; KP = 128; b0 = 208; }
    else              { W = s5; D = d5; din = 128; KP = 128; b0 = 272; }
    int idx = (b - b0) * 256 + threadIdx.x;
    if (idx >= KP * 128) return;
    int j = idx & 7;
    int lane = (idx >> 3) & 63;
    int rest = idx >> 9;
    int KS = KP >> 5;
    int kstep = rest % KS;
    int tile = rest / KS;
    int k = kstep * 32 + ((lane >> 4) * 8) + j;
    int n = tile * 16 + (lane & 15);
    float v = (k < din) ? W[k * 128 + n] : 0.f;
    D[idx] = (short)to_bf(v);
}

// ---------------- Fused layer: gather + MFMA MLP + reg-LN + ReLU (+pool) ----------------
// 128 threads = 2 waves; 32 nodes/block; each wave owns its 16 rows end-to-end.
// Non-pool layers: ONE barrier total (eweb staging) -- waves fully decoupled after it.
// __launch_bounds__(128,4): VGPR cap 128 -> compiler ~64, NO SPILL (caps >4 waves/EU spill: R9/R11/R13).
template <int KP1, bool POOL>
__global__ __launch_bounds__(128, 4) void layer_fused(
    const void* __restrict__ xin_v, const int* __restrict__ row_ptr,
    const int2* __restrict__ csr,
    const float* __restrict__ ew, const float* __restrict__ eb,
    const short* __restrict__ w1h, const float* __restrict__ b1,
    const short* __restrict__ w2h, const float* __restrict__ b2,
    const float* __restrict__ g, const float* __restrict__ bt,
    unsigned short* __restrict__ xout,
    const int* __restrict__ batch, float* __restrict__ pool, int* __restrict__ cnt) {
    __shared__ __align__(16) unsigned short A16[NPBLK * LDA];
    __shared__ int bidx[NPBLK];
    union Scratch {
        float eweb[256];                    // [0..127]=ew, [128..255]=eb  (din=128 path)
        float part[NPBLK][4][INDIM];        // layer-0 gather partials
    };
    __shared__ Scratch u;

    int tid = threadIdx.x;
    int node0 = blockIdx.x * NPBLK;

    if (KP1 == 128) {
        const unsigned short* xin = (const unsigned short*)xin_v;
        // stage ew/eb to LDS
        if (tid < 32) ((float4*)u.eweb)[tid] = ((const float4*)ew)[tid];
        else if (tid < 64) ((float4*)u.eweb)[tid] = ((const float4*)eb)[tid - 32];
        if (POOL && tid >= 64 && tid < 96) bidx[tid - 64] = batch[node0 + tid - 64];

        // thread = (row, 32-channel quarter); f32 accumulators in registers
        int row = tid >> 2, qt = tid & 3, c0 = qt * 32;
        int node = node0 + row;
        float acc[32];
        {
            const uint4* xn = (const uint4*)(xin + (size_t)node * 128 + c0);
            uint4 uv[4];
#pragma unroll
            for (int j = 0; j < 4; ++j) uv[j] = xn[j];
            unsigned wds[16] = {uv[0].x, uv[0].y, uv[0].z, uv[0].w,
                                uv[1].x, uv[1].y, uv[1].z, uv[1].w,
                                uv[2].x, uv[2].y, uv[2].z, uv[2].w,
                                uv[3].x, uv[3].y, uv[3].z, uv[3].w};
#pragma unroll
            for (int i = 0; i < 16; ++i) {
                acc[2 * i] = bf_lo(wds[i]);
                acc[2 * i + 1] = bf_hi(wds[i]);
            }
        }
        int beg = row_ptr[node], end = row_ptr[node + 1];
        __syncthreads();  // eweb ready (the only barrier on this path)

        for (int e = beg; e < end; ++e) {
            int2 r = csr[e];
            float a = __int_as_float(r.y);
            const uint4* xs = (const uint4*)(xin + (size_t)r.x * 128 + c0);
            uint4 uv[4];
#pragma unroll
            for (int j = 0; j < 4; ++j) uv[j] = xs[j];
            unsigned wds[16] = {uv[0].x, uv[0].y, uv[0].z, uv[0].w,
                                uv[1].x, uv[1].y, uv[1].z, uv[1].w,
                                uv[2].x, uv[2].y, uv[2].z, uv[2].w,
                                uv[3].x, uv[3].y, uv[3].z, uv[3].w};
#pragma unroll
            for (int i = 0; i < 16; ++i) {
                int cA = c0 + 2 * i, cB = cA + 1;
                acc[2 * i] += fmaxf(fmaf(a, u.eweb[cA], bf_lo(wds[i]) + u.eweb[128 + cA]), 0.f);
                acc[2 * i + 1] += fmaxf(fmaf(a, u.eweb[cB], bf_hi(wds[i]) + u.eweb[128 + cB]), 0.f);
            }
        }
        unsigned* Ar = (unsigned*)&A16[row * LDA + c0];
#pragma unroll
        for (int i = 0; i < 16; ++i)
            Ar[i] = (unsigned)to_bf(acc[2 * i]) | ((unsigned)to_bf(acc[2 * i + 1]) << 16);
        // no barrier: rows [16wv,16wv+16) are written and read by the same wave
    } else {
        // layer 0 (din=5): 4 threads/row split the edge list; register partials
        const float* xinf = (const float*)xin_v;
        int row = tid >> 2, qt = tid & 3;
        int node = node0 + row;
        if (POOL && tid >= 64 && tid < 96) bidx[tid - 64] = batch[node0 + tid - 64];
        {
            float w[INDIM], b[INDIM], acc[INDIM];
#pragma unroll
            for (int j = 0; j < INDIM; ++j) {
                w[j] = ew[j];
                b[j] = eb[j];
                acc[j] = 0.f;
            }
            int beg = row_ptr[node], end = row_ptr[node + 1];
            for (int e = beg + qt; e < end; e += 4) {
                int2 r = csr[e];
                float a = __int_as_float(r.y);
#pragma unroll
                for (int j = 0; j < INDIM; ++j)
                    acc[j] += fmaxf(fmaf(a, w[j], xinf[r.x * INDIM + j] + b[j]), 0.f);
            }
#pragma unroll
            for (int j = 0; j < INDIM; ++j) u.part[row][qt][j] = acc[j];
        }
        __syncthreads();
        if (tid < NPBLK) {
#pragma unroll
            for (int j = 0; j < INDIM; ++j) {
                float v = xinf[(node0 + tid) * INDIM + j] + u.part[tid][0][j] + u.part[tid][1][j] +
                          u.part[tid][2][j] + u.part[tid][3][j];
                A16[tid * LDA + j] = to_bf(v);
            }
#pragma unroll
            for (int j = INDIM; j < 32; ++j) A16[tid * LDA + j] = 0;
        }
        __syncthreads();  // rows written by wave0 only -> cross-wave
    }

    // ---- MFMA MLP (wave-local rows) ----
    int wv = tid >> 6, lane = tid & 63;
    int mrow = lane & 15, q = lane >> 4;
    int arow = wv * 16 + mrow;

    const short8* w1p = (const short8*)w1h;
    const short8* w2p = (const short8*)w2h;

    f32x4 acc2[8];
#pragma unroll
    for (int t = 0; t < 8; ++t) acc2[t] = (f32x4){0.f, 0.f, 0.f, 0.f};
    constexpr int KS1 = KP1 / 32;
#pragma unroll
    for (int ks = 0; ks < KS1; ++ks) {
        short8 bh[8];
#pragma unroll
        for (int t = 0; t < 8; ++t) bh[t] = w1p[((size_t)t * KS1 + ks) * 64 + lane];
        short8 ah = *(const short8*)&A16[arow * LDA + ks * 32 + q * 8];
#pragma unroll
        for (int t = 0; t < 8; ++t)
            acc2[t] = __builtin_amdgcn_mfma_f32_16x16x32_bf16(ah, bh[t], acc2[t], 0, 0, 0);
    }
    // t1 = relu(acc + b1) -> bf16 A (wave-local rows)
    {
        float b1v[8];
#pragma unroll
        for (int t = 0; t < 8; ++t) b1v[t] = b1[t * 16 + mrow];
#pragma unroll
        for (int t = 0; t < 8; ++t)
#pragma unroll
            for (int r = 0; r < 4; ++r) {
                int rrow = wv * 16 + q * 4 + r;
                int col = t * 16 + mrow;
                A16[rrow * LDA + col] = to_bf(fmaxf(acc2[t][r] + b1v[t], 0.f));
            }
    }

    // GEMM2 (K = 128); A reads wave-local
#pragma unroll
    for (int t = 0; t < 8; ++t) acc2[t] = (f32x4){0.f, 0.f, 0.f, 0.f};
#pragma unroll
    for (int ks = 0; ks < 4; ++ks) {
        short8 bh[8];
#pragma unroll
        for (int t = 0; t < 8; ++t) bh[t] = w2p[((size_t)t * 4 + ks) * 64 + lane];
        short8 ah = *(const short8*)&A16[arow * LDA + ks * 32 + q * 8];
#pragma unroll
        for (int t = 0; t < 8; ++t)
            acc2[t] = __builtin_amdgcn_mfma_f32_16x16x32_bf16(ah, bh[t], acc2[t], 0, 0, 0);
    }

    // ---- LayerNorm in registers (rows live in 16-lane groups) ----
    float s4[4] = {0.f, 0.f, 0.f, 0.f}, q4[4] = {0.f, 0.f, 0.f, 0.f};
    {
        float b2v[8];
#pragma unroll
        for (int t = 0; t < 8; ++t) b2v[t] = b2[t * 16 + mrow];
#pragma unroll
        for (int t = 0; t < 8; ++t)
#pragma unroll
            for (int r = 0; r < 4; ++r) {
                float v = acc2[t][r] + b2v[t];
                acc2[t][r] = v;
                s4[r] += v;
                q4[r] += v * v;
            }
    }
#pragma unroll
    for (int m = 1; m <= 8; m <<= 1) {
#pragma unroll
        for (int r = 0; r < 4; ++r) {
            s4[r] += __shfl_xor(s4[r], m, 64);
            q4[r] += __shfl_xor(q4[r], m, 64);
        }
    }
    float mu[4], inv[4];
#pragma unroll
    for (int r = 0; r < 4; ++r) {
        mu[r] = s4[r] * (1.f / HDIM);
        float var = q4[r] * (1.f / HDIM) - mu[r] * mu[r];
        inv[r] = rsqrtf(var + LN_EPS);
    }
    float gv[8], btv[8];
#pragma unroll
    for (int t = 0; t < 8; ++t) {
        gv[t] = g[t * 16 + mrow];
        btv[t] = bt[t * 16 + mrow];
    }

    // LN result -> LDS (wave-local row writes)
#pragma unroll
    for (int t = 0; t < 8; ++t)
#pragma unroll
        for (int r = 0; r < 4; ++r) {
            int rrow = wv * 16 + q * 4 + r;
            int col = t * 16 + mrow;
            float o = fmaxf((acc2[t][r] - mu[r]) * inv[r] * gv[t] + btv[t], 0.f);
            A16[rrow * LDA + col] = to_bf(o);
        }

    if (!POOL) {
        // wave-local coalesced copy-out: each wave stores only its own 16 rows.
        // One wave-inst = 64 lanes x 4B = one full 256-B row. NO block barrier.
        unsigned* xo = (unsigned*)xout;
#pragma unroll
        for (int rr = 0; rr < 16; ++rr) {
            int row = wv * 16 + rr;
            xo[(size_t)(node0 + row) * 64 + lane] = ((const unsigned*)&A16[row * LDA])[lane];
        }
    } else {
        __syncthreads();  // pool scan reads all 32 rows
        {
            int col = tid;  // 128 threads = 128 cols
            float accp = 0.f;
            int cur = bidx[0];
            for (int r = 0; r < NPBLK; ++r) {
                int gi = bidx[r];
                if (gi != cur) {
                    unsafeAtomicAdd(&pool[cur * HDIM + col], accp);
                    accp = 0.f;
                    cur = gi;
                }
                accp += bf2f(A16[r * LDA + col]);
            }
            unsafeAtomicAdd(&pool[cur * HDIM + col], accp);
        }
        if (tid == 0) {
            int cur = bidx[0], c = 0;
            for (int r = 0; r < NPBLK; ++r) {
                if (bidx[r] != cur) {
                    atomicAdd(&cnt[cur], c);
                    c = 0;
                    cur = bidx[r];
                }
                ++c;
            }
            atomicAdd(&cnt[cur], c);
        }
    }
}

__global__ void pool_final(const float* __restrict__ pool, const int* __restrict__ cnt,
                           float* __restrict__ out) {
    int g = blockIdx.x, j = threadIdx.x;
    float add = pool[g * HDIM + j];
    float c = (float)max(cnt[g], 1);
    out[g * (2 * HDIM) + j] = add / c;
    out[g * (2 * HDIM) + HDIM + j] = add;
}

extern "C" void kernel_launch(void* const* d_in, const int* in_sizes, int n_in,
                              void* d_out, int out_size, void* d_ws, size_t ws_size,
                              hipStream_t stream) {
    const float* x_in = (const float*)d_in[0];
    const int* ei = (const int*)d_in[1];
    const float* ea = (const float*)d_in[2];
    const int* batch = (const int*)d_in[3];
    const float* P[24];
    for (int i = 0; i < 24; ++i) P[i] = (const float*)d_in[4 + i];
    // per layer l (base 8l): 0=ew 1=eb 2=w1 3=b1 4=w2 5=b2 6=g 7=bt

    unsigned short* x_a = (unsigned short*)d_ws;                 // N*128 bf16
    unsigned short* x_b = x_a + (size_t)N_NODES * HDIM;          // N*128 bf16
    float* pool = (float*)(x_b + (size_t)N_NODES * HDIM);        // G*128 } zeroed
    int* cnt = (int*)(pool + N_GRAPHS * HDIM);                   // G     } together
    int* deg = cnt + N_GRAPHS;                                   // N
    int* cursor = deg + N_NODES;                                 // N
    int* row_ptr = cursor + N_NODES;                             // N+1
    int* bsums = row_ptr + N_NODES + 1;                          // pad 256 (keeps int2 8B-aligned)
    int2* csr = (int2*)(bsums + 256);                            // E (packed {src, val})
    short* wp = (short*)(((uintptr_t)(csr + N_EDGES) + 15) & ~(uintptr_t)15);
    float* out = (float*)d_out;

    short *w1h[3], *w2h[3];
    for (int l = 0; l < 3; ++l) {
        w1h[l] = wp + (size_t)l * 32768;
        w2h[l] = w1h[l] + 16384;
    }

    // ---- single memset: pool + cnt + deg + cursor ----
    hipMemsetAsync(pool, 0,
                   (N_GRAPHS * HDIM + N_GRAPHS + 2 * N_NODES) * sizeof(int), stream);

    // ---- CSR build ----
    hist_kernel<<<(N_EDGES + 255) / 256, 256, 0, stream>>>(ei, deg);
    scan_phaseA<<<SCAN_BLOCKS, 256, 0, stream>>>(deg, bsums);
    scan_phaseB<<<1, 256, 0, stream>>>(bsums, row_ptr);
    scan_phaseC<<<SCAN_BLOCKS, 256, 0, stream>>>(deg, bsums, row_ptr);
    scatter_kernel<<<(N_EDGES + 255) / 256, 256, 0, stream>>>(ei, ea, row_ptr, cursor, csr);

    // ---- pack all weights in one launch (16 + 5*64 = 336 blocks) ----
    pack_all<<<336, 256, 0, stream>>>(P[2], w1h[0], P[4], w2h[0],
                                      P[10], w1h[1], P[12], w2h[1],
                                      P[18], w1h[2], P[20], w2h[2]);

    // ---- fused layers ----
    layer_fused<32, false><<<N_NODES / NPBLK, 128, 0, stream>>>(
        x_in, row_ptr, csr, P[0], P[1],
        w1h[0], P[3], w2h[0], P[5], P[6], P[7], x_a, nullptr, nullptr, nullptr);
    layer_fused<128, false><<<N_NODES / NPBLK, 128, 0, stream>>>(
        x_a, row_ptr, csr, P[8], P[9],
        w1h[1], P[11], w2h[1], P[13], P[14], P[15], x_b, nullptr, nullptr, nullptr);
    layer_fused<128, true><<<N_NODES / NPBLK, 128, 0, stream>>>(
        x_b, row_ptr, csr, P[16], P[17],
        w1h[2], P[19], w2h[2], P[21], P[22], P[23], nullptr, batch, pool, cnt);

    pool_final<<<N_GRAPHS, HDIM, 0, stream>>>(pool, cnt, out);
}

// Round 15
// 342.100 us; speedup vs baseline: 1.3435x; 1.0695x over previous
//
#include <hip/hip_runtime.h>

#define N_NODES 200000
#define N_EDGES 400000
#define N_GRAPHS 64
#define HDIM 128
#define INDIM 5
#define LN_EPS 1e-5f
#define LDA 138  // 69 words/row, 69 mod 32 = 5 (coprime) -> conflict-distributed LDS reads
#define NPBLK 64 // nodes per block (4 waves x 16 rows) -- R12 verified config

typedef __attribute__((ext_vector_type(8))) short short8;
typedef __attribute__((ext_vector_type(4))) float f32x4;

__device__ __forceinline__ unsigned short to_bf(float v) {
    unsigned u = __builtin_bit_cast(unsigned, v);
    return (unsigned short)((u + 0x7FFFu + ((u >> 16) & 1u)) >> 16);
}
__device__ __forceinline__ float bf_lo(unsigned w) { return __builtin_bit_cast(float, w << 16); }
__device__ __forceinline__ float bf_hi(unsigned w) { return __builtin_bit_cast(float, w & 0xFFFF0000u); }
__device__ __forceinline__ float bf2f(unsigned short h) { return __builtin_bit_cast(float, (unsigned)h << 16); }

// ---------------- CSR build ----------------

__global__ void hist_kernel(const int* __restrict__ ei, int* __restrict__ deg) {
    int e = blockIdx.x * blockDim.x + threadIdx.x;
    if (e < N_EDGES) atomicAdd(&deg[ei[N_EDGES + e]], 1);
}

#define SCAN_CHUNK 1024
#define SCAN_BLOCKS ((N_NODES + SCAN_CHUNK - 1) / SCAN_CHUNK)  // 196

// also zeroes pool+cnt (block 0) -- saves a memset range
__global__ __launch_bounds__(256) void scan_phaseA(const int* __restrict__ deg, int* __restrict__ bsums,
                                                   int* __restrict__ poolz) {
    if (blockIdx.x == 0) {
        for (int i = threadIdx.x; i < N_GRAPHS * HDIM + N_GRAPHS; i += 256) poolz[i] = 0;
    }
    __shared__ int red[256];
    int t = threadIdx.x;
    int base = blockIdx.x * SCAN_CHUNK + t * 4;
    int s = 0;
#pragma unroll
    for (int k = 0; k < 4; ++k) {
        int i = base + k;
        s += (i < N_NODES) ? deg[i] : 0;
    }
    red[t] = s;
    __syncthreads();
    for (int off = 128; off; off >>= 1) {
        if (t < off) red[t] += red[t + off];
        __syncthreads();
    }
    if (t == 0) bsums[blockIdx.x] = red[0];
}

__global__ __launch_bounds__(256) void scan_phaseB(int* __restrict__ bsums, int* __restrict__ row_ptr) {
    __shared__ int s[256];
    int t = threadIdx.x;
    int v = (t < SCAN_BLOCKS) ? bsums[t] : 0;
    s[t] = v;
    __syncthreads();
    for (int off = 1; off < 256; off <<= 1) {
        int add = (t >= off) ? s[t - off] : 0;
        __syncthreads();
        s[t] += add;
        __syncthreads();
    }
    if (t < SCAN_BLOCKS) bsums[t] = s[t] - v;  // exclusive
    if (t == SCAN_BLOCKS - 1) row_ptr[N_NODES] = s[t];
}

// also zeroes cursor -- saves a memset range
__global__ __launch_bounds__(256) void scan_phaseC(const int* __restrict__ deg,
                                                   const int* __restrict__ bsums,
                                                   int* __restrict__ row_ptr,
                                                   int* __restrict__ cursor) {
    __shared__ int ts[256];
    int t = threadIdx.x;
    int base = blockIdx.x * SCAN_CHUNK + t * 4;
    int v[4];
    int s = 0;
#pragma unroll
    for (int k = 0; k < 4; ++k) {
        int i = base + k;
        v[k] = (i < N_NODES) ? deg[i] : 0;
        s += v[k];
    }
    ts[t] = s;
    __syncthreads();
    for (int off = 1; off < 256; off <<= 1) {
        int add = (t >= off) ? ts[t - off] : 0;
        __syncthreads();
        ts[t] += add;
        __syncthreads();
    }
    int run = bsums[blockIdx.x] + ts[t] - s;
#pragma unroll
    for (int k = 0; k < 4; ++k) {
        int i = base + k;
        if (i < N_NODES) { row_ptr[i] = run; cursor[i] = 0; }
        run += v[k];
    }
}

// ---------------- Fused scatter (CSR fill) + weight packing ----------------
#define SCATTER_BLOCKS ((N_EDGES + 255) / 256)  // 1563

__global__ void scatter_pack(const int* __restrict__ ei, const float* __restrict__ ea,
                             const int* __restrict__ row_ptr, int* __restrict__ cursor,
                             int2* __restrict__ csr,
                             const float* __restrict__ s0, short* __restrict__ d0,
                             const float* __restrict__ s1, short* __restrict__ d1,
                             const float* __restrict__ s2, short* __restrict__ d2,
                             const float* __restrict__ s3, short* __restrict__ d3,
                             const float* __restrict__ s4, short* __restrict__ d4,
                             const float* __restrict__ s5, short* __restrict__ d5) {
    int b = blockIdx.x;
    if (b < SCATTER_BLOCKS) {
        int e = b * 256 + threadIdx.x;
        if (e >= N_EDGES) return;
        int d = ei[N_EDGES + e];
        int pos = atomicAdd(&cursor[d], 1);
        csr[row_ptr[d] + pos] = make_int2(ei[e], __float_as_int(ea[e]));
        return;
    }
    b -= SCATTER_BLOCKS;
    const float* W;
    short* D;
    int din, KP, b0;
    if (b < 16)       { W = s0; D = d0; din = 5;   KP = 32;  b0 = 0; }
    else if (b < 80)  { W = s1; D = d1; din = 128; KP = 128; b0 = 16; }
    else if (b < 144) { W = s2; D = d2; din = 128; KP = 128; b0 = 80; }
    else if (b < 208) { W = s3; D = d3; din = 128; KP = 128; b0 = 144; }
    else if (b < 272) { W = s4; D = d4; din = 128; KP = 128; b0 = 208; }
    else              { W = s5; D = d5; din = 128; KP = 128; b0 = 272; }
    int idx = (b - b0) * 256 + threadIdx.x;
    if (idx >= KP * 128) return;
    int j = idx & 7;
    int lane = (idx >> 3) & 63;
    int rest = idx >> 9;
    int KS = KP >> 5;
    int kstep = rest % KS;
    int tile = rest / KS;
    int k = kstep * 32 + ((lane >> 4) * 8) + j;
    int n = tile * 16 + (lane & 15);
    float v = (k < din) ? W[k * 128 + n] : 0.f;
    D[idx] = (short)to_bf(v);
}

// ---------------- Fused layer: gather + MFMA MLP + reg-LN + ReLU (+pool) ----------------
// 256 threads = 4 waves; 64 nodes/block. (256,4): VGPR cap 128 -> ~64, no spill
// (any min-waves >4 under-allocates and spills: R9/R11/R13 evidence).
template <int KP1, bool POOL>
__global__ __launch_bounds__(256, 4) void layer_fused(
    const void* __restrict__ xin_v, const int* __restrict__ row_ptr,
    const int2* __restrict__ csr,
    const float* __restrict__ ew, const float* __restrict__ eb,
    const short* __restrict__ w1h, const float* __restrict__ b1,
    const short* __restrict__ w2h, const float* __restrict__ b2,
    const float* __restrict__ g, const float* __restrict__ bt,
    unsigned short* __restrict__ xout,
    const int* __restrict__ batch, float* __restrict__ pool, int* __restrict__ cnt) {
    __shared__ __align__(16) unsigned short A16[NPBLK * LDA];
    __shared__ int bidx[NPBLK];
    union Scratch {
        float eweb[256];                    // [0..127]=ew, [128..255]=eb  (din=128 path)
        float part[NPBLK][4][INDIM];        // layer-0 gather partials
    };
    __shared__ Scratch u;

    int tid = threadIdx.x;
    int node0 = blockIdx.x * NPBLK;

    if (KP1 == 128) {
        const unsigned short* xin = (const unsigned short*)xin_v;
        // stage ew/eb to LDS
        if (tid < 32) ((float4*)u.eweb)[tid] = ((const float4*)ew)[tid];
        else if (tid < 64) ((float4*)u.eweb)[tid] = ((const float4*)eb)[tid - 32];
        if (POOL && tid >= 64 && tid < 128) bidx[tid - 64] = batch[node0 + tid - 64];

        // thread = (row, 32-channel quarter); f32 accumulators in registers
        int row = tid >> 2, qt = tid & 3, c0 = qt * 32;
        int node = node0 + row;
        float acc[32];
        {
            const uint4* xn = (const uint4*)(xin + (size_t)node * 128 + c0);
            uint4 uv[4];
#pragma unroll
            for (int j = 0; j < 4; ++j) uv[j] = xn[j];
            unsigned wds[16] = {uv[0].x, uv[0].y, uv[0].z, uv[0].w,
                                uv[1].x, uv[1].y, uv[1].z, uv[1].w,
                                uv[2].x, uv[2].y, uv[2].z, uv[2].w,
                                uv[3].x, uv[3].y, uv[3].z, uv[3].w};
#pragma unroll
            for (int i = 0; i < 16; ++i) {
                acc[2 * i] = bf_lo(wds[i]);
                acc[2 * i + 1] = bf_hi(wds[i]);
            }
        }
        int beg = row_ptr[node], end = row_ptr[node + 1];
        __syncthreads();  // eweb ready

        // gather with csr-record prefetch: next record load overlaps this edge's x-row wait
        int2 r;
        if (beg < end) r = csr[beg];
        for (int e = beg; e < end; ++e) {
            int2 rn = (e + 1 < end) ? csr[e + 1] : r;
            float a = __int_as_float(r.y);
            const uint4* xs = (const uint4*)(xin + (size_t)r.x * 128 + c0);
            uint4 uv[4];
#pragma unroll
            for (int j = 0; j < 4; ++j) uv[j] = xs[j];
            unsigned wds[16] = {uv[0].x, uv[0].y, uv[0].z, uv[0].w,
                                uv[1].x, uv[1].y, uv[1].z, uv[1].w,
                                uv[2].x, uv[2].y, uv[2].z, uv[2].w,
                                uv[3].x, uv[3].y, uv[3].z, uv[3].w};
#pragma unroll
            for (int i = 0; i < 16; ++i) {
                int cA = c0 + 2 * i, cB = cA + 1;
                acc[2 * i] += fmaxf(fmaf(a, u.eweb[cA], bf_lo(wds[i]) + u.eweb[128 + cA]), 0.f);
                acc[2 * i + 1] += fmaxf(fmaf(a, u.eweb[cB], bf_hi(wds[i]) + u.eweb[128 + cB]), 0.f);
            }
            r = rn;
        }
        unsigned* Ar = (unsigned*)&A16[row * LDA + c0];
#pragma unroll
        for (int i = 0; i < 16; ++i)
            Ar[i] = (unsigned)to_bf(acc[2 * i]) | ((unsigned)to_bf(acc[2 * i + 1]) << 16);
        // no barrier: rows [16wv,16wv+16) are written and read by the same wave
    } else {
        // layer 0 (din=5): 4 threads/row split the edge list; register partials
        const float* xinf = (const float*)xin_v;
        int row = tid >> 2, qt = tid & 3;
        int node = node0 + row;
        {
            float w[INDIM], b[INDIM], acc[INDIM];
#pragma unroll
            for (int j = 0; j < INDIM; ++j) {
                w[j] = ew[j];
                b[j] = eb[j];
                acc[j] = 0.f;
            }
            int beg = row_ptr[node], end = row_ptr[node + 1];
            int2 r;
            if (beg + qt < end) r = csr[beg + qt];
            for (int e = beg + qt; e < end; e += 4) {
                int2 rn = (e + 4 < end) ? csr[e + 4] : r;
                float a = __int_as_float(r.y);
#pragma unroll
                for (int j = 0; j < INDIM; ++j)
                    acc[j] += fmaxf(fmaf(a, w[j], xinf[r.x * INDIM + j] + b[j]), 0.f);
                r = rn;
            }
#pragma unroll
            for (int j = 0; j < INDIM; ++j) u.part[row][qt][j] = acc[j];
        }
        __syncthreads();
        if (tid < NPBLK) {
#pragma unroll
            for (int j = 0; j < INDIM; ++j) {
                float v = xinf[(node0 + tid) * INDIM + j] + u.part[tid][0][j] + u.part[tid][1][j] +
                          u.part[tid][2][j] + u.part[tid][3][j];
                A16[tid * LDA + j] = to_bf(v);
            }
#pragma unroll
            for (int j = INDIM; j < 32; ++j) A16[tid * LDA + j] = 0;
        }
        __syncthreads();  // rows written by tid<64 -> cross-wave
    }

    // ---- MFMA MLP (wave-local rows) ----
    int wv = tid >> 6, lane = tid & 63;
    int mrow = lane & 15, q = lane >> 4;
    int arow = wv * 16 + mrow;

    const short8* w1p = (const short8*)w1h;
    const short8* w2p = (const short8*)w2h;

    f32x4 acc2[8];
#pragma unroll
    for (int t = 0; t < 8; ++t) acc2[t] = (f32x4){0.f, 0.f, 0.f, 0.f};
    constexpr int KS1 = KP1 / 32;
#pragma unroll
    for (int ks = 0; ks < KS1; ++ks) {
        short8 bh[8];
#pragma unroll
        for (int t = 0; t < 8; ++t) bh[t] = w1p[((size_t)t * KS1 + ks) * 64 + lane];
        short8 ah = *(const short8*)&A16[arow * LDA + ks * 32 + q * 8];
#pragma unroll
        for (int t = 0; t < 8; ++t)
            acc2[t] = __builtin_amdgcn_mfma_f32_16x16x32_bf16(ah, bh[t], acc2[t], 0, 0, 0);
    }
    // t1 = relu(acc + b1) -> bf16 A (wave-local rows)
    {
        float b1v[8];
#pragma unroll
        for (int t = 0; t < 8; ++t) b1v[t] = b1[t * 16 + mrow];
#pragma unroll
        for (int t = 0; t < 8; ++t)
#pragma unroll
            for (int r = 0; r < 4; ++r) {
                int rrow = wv * 16 + q * 4 + r;
                int col = t * 16 + mrow;
                A16[rrow * LDA + col] = to_bf(fmaxf(acc2[t][r] + b1v[t], 0.f));
            }
    }

    // GEMM2 (K = 128); A reads wave-local
#pragma unroll
    for (int t = 0; t < 8; ++t) acc2[t] = (f32x4){0.f, 0.f, 0.f, 0.f};
#pragma unroll
    for (int ks = 0; ks < 4; ++ks) {
        short8 bh[8];
#pragma unroll
        for (int t = 0; t < 8; ++t) bh[t] = w2p[((size_t)t * 4 + ks) * 64 + lane];
        short8 ah = *(const short8*)&A16[arow * LDA + ks * 32 + q * 8];
#pragma unroll
        for (int t = 0; t < 8; ++t)
            acc2[t] = __builtin_amdgcn_mfma_f32_16x16x32_bf16(ah, bh[t], acc2[t], 0, 0, 0);
    }

    // ---- LayerNorm in registers (rows live in 16-lane groups) ----
    float s4[4] = {0.f, 0.f, 0.f, 0.f}, q4[4] = {0.f, 0.f, 0.f, 0.f};
    {
        float b2v[8];
#pragma unroll
        for (int t = 0; t < 8; ++t) b2v[t] = b2[t * 16 + mrow];
#pragma unroll
        for (int t = 0; t < 8; ++t)
#pragma unroll
            for (int r = 0; r < 4; ++r) {
                float v = acc2[t][r] + b2v[t];
                acc2[t][r] = v;
                s4[r] += v;
                q4[r] += v * v;
            }
    }
#pragma unroll
    for (int m = 1; m <= 8; m <<= 1) {
#pragma unroll
        for (int r = 0; r < 4; ++r) {
            s4[r] += __shfl_xor(s4[r], m, 64);
            q4[r] += __shfl_xor(q4[r], m, 64);
        }
    }
    float mu[4], inv[4];
#pragma unroll
    for (int r = 0; r < 4; ++r) {
        mu[r] = s4[r] * (1.f / HDIM);
        float var = q4[r] * (1.f / HDIM) - mu[r] * mu[r];
        inv[r] = rsqrtf(var + LN_EPS);
    }
    float gv[8], btv[8];
#pragma unroll
    for (int t = 0; t < 8; ++t) {
        gv[t] = g[t * 16 + mrow];
        btv[t] = bt[t * 16 + mrow];
    }

    // LN result -> LDS (wave-local row writes; no pre-barrier needed)
#pragma unroll
    for (int t = 0; t < 8; ++t)
#pragma unroll
        for (int r = 0; r < 4; ++r) {
            int rrow = wv * 16 + q * 4 + r;
            int col = t * 16 + mrow;
            float o = fmaxf((acc2[t][r] - mu[r]) * inv[r] * gv[t] + btv[t], 0.f);
            A16[rrow * LDA + col] = to_bf(o);
        }
    __syncthreads();  // epilogue reads all rows (cross-wave)

    if (!POOL) {
        // coalesced copy-out: wave inst covers 256 contiguous bytes (4 full lines)
        unsigned* xo = (unsigned*)xout;
#pragma unroll
        for (int i = 0; i < 16; ++i) {
            int idx = tid + 256 * i;       // 4096 = 64 rows x 64 words
            int row = idx >> 6, w = idx & 63;
            xo[(size_t)(node0 + row) * 64 + w] = ((const unsigned*)&A16[row * LDA])[w];
        }
    } else {
        if (tid < 128) {
            int col = tid;
            float accp = 0.f;
            int cur = bidx[0];
            for (int r = 0; r < NPBLK; ++r) {
                int gi = bidx[r];
                if (gi != cur) {
                    unsafeAtomicAdd(&pool[cur * HDIM + col], accp);
                    accp = 0.f;
                    cur = gi;
                }
                accp += bf2f(A16[r * LDA + col]);
            }
            unsafeAtomicAdd(&pool[cur * HDIM + col], accp);
        } else if (tid == 255) {
            int cur = bidx[0], c = 0;
            for (int r = 0; r < NPBLK; ++r) {
                if (bidx[r] != cur) {
                    atomicAdd(&cnt[cur], c);
                    c = 0;
                    cur = bidx[r];
                }
                ++c;
            }
            atomicAdd(&cnt[cur], c);
        }
    }
}

__global__ void pool_final(const float* __restrict__ pool, const int* __restrict__ cnt,
                           float* __restrict__ out) {
    int g = blockIdx.x, j = threadIdx.x;
    float add = pool[g * HDIM + j];
    float c = (float)max(cnt[g], 1);
    out[g * (2 * HDIM) + j] = add / c;
    out[g * (2 * HDIM) + HDIM + j] = add;
}

extern "C" void kernel_launch(void* const* d_in, const int* in_sizes, int n_in,
                              void* d_out, int out_size, void* d_ws, size_t ws_size,
                              hipStream_t stream) {
    const float* x_in = (const float*)d_in[0];
    const int* ei = (const int*)d_in[1];
    const float* ea = (const float*)d_in[2];
    const int* batch = (const int*)d_in[3];
    const float* P[24];
    for (int i = 0; i < 24; ++i) P[i] = (const float*)d_in[4 + i];
    // per layer l (base 8l): 0=ew 1=eb 2=w1 3=b1 4=w2 5=b2 6=g 7=bt

    unsigned short* x_a = (unsigned short*)d_ws;                 // N*128 bf16
    unsigned short* x_b = x_a + (size_t)N_NODES * HDIM;          // N*128 bf16
    float* pool = (float*)(x_b + (size_t)N_NODES * HDIM);        // G*128 (zeroed in scanA)
    int* cnt = (int*)(pool + N_GRAPHS * HDIM);                   // G    (zeroed in scanA)
    int* deg = cnt + N_GRAPHS;                                   // N    (memset)
    int* cursor = deg + N_NODES;                                 // N    (zeroed in scanC)
    int* row_ptr = cursor + N_NODES;                             // N+1
    int* bsums = row_ptr + N_NODES + 1;                          // pad 256 (keeps int2 8B-aligned)
    int2* csr = (int2*)(bsums + 256);                            // E (packed {src, val})
    short* wp = (short*)(((uintptr_t)(csr + N_EDGES) + 15) & ~(uintptr_t)15);
    float* out = (float*)d_out;

    short *w1h[3], *w2h[3];
    for (int l = 0; l < 3; ++l) {
        w1h[l] = wp + (size_t)l * 32768;
        w2h[l] = w1h[l] + 16384;
    }

    // ---- memset: deg only (pool/cnt zeroed in scanA, cursor in scanC) ----
    hipMemsetAsync(deg, 0, N_NODES * sizeof(int), stream);

    // ---- CSR build ----
    hist_kernel<<<(N_EDGES + 255) / 256, 256, 0, stream>>>(ei, deg);
    scan_phaseA<<<SCAN_BLOCKS, 256, 0, stream>>>(deg, bsums, (int*)pool);
    scan_phaseB<<<1, 256, 0, stream>>>(bsums, row_ptr);
    scan_phaseC<<<SCAN_BLOCKS, 256, 0, stream>>>(deg, bsums, row_ptr, cursor);

    // ---- fused scatter + weight packing (1563 + 336 blocks) ----
    scatter_pack<<<SCATTER_BLOCKS + 336, 256, 0, stream>>>(
        ei, ea, row_ptr, cursor, csr,
        P[2], w1h[0], P[4], w2h[0],
        P[10], w1h[1], P[12], w2h[1],
        P[18], w1h[2], P[20], w2h[2]);

    // ---- fused layers ----
    layer_fused<32, false><<<N_NODES / NPBLK, 256, 0, stream>>>(
        x_in, row_ptr, csr, P[0], P[1],
        w1h[0], P[3], w2h[0], P[5], P[6], P[7], x_a, nullptr, nullptr, nullptr);
    layer_fused<128, false><<<N_NODES / NPBLK, 256, 0, stream>>>(
        x_a, row_ptr, csr, P[8], P[9],
        w1h[1], P[11], w2h[1], P[13], P[14], P[15], x_b, nullptr, nullptr, nullptr);
    layer_fused<128, true><<<N_NODES / NPBLK, 256, 0, stream>>>(
        x_b, row_ptr, csr, P[16], P[17],
        w1h[2], P[19], w2h[2], P[21], P[22], P[23], nullptr, batch, pool, cnt);

    pool_final<<<N_GRAPHS, HDIM, 0, stream>>>(pool, cnt, out);
}